// Round 1
// baseline (339.587 us; speedup 1.0000x reference)
//
#include <hip/hip_runtime.h>
#include <hip/hip_bf16.h>

#define N_NODES 100000
#define N_EDGES 800000
#define D 128
#define NH 8
#define NB ((N_NODES + 255) / 256)   // 391 scan blocks

typedef __hip_bfloat16 bf16;
typedef __bf16 bf16x8 __attribute__((ext_vector_type(8)));
typedef float  f32x4  __attribute__((ext_vector_type(4)));

__device__ __forceinline__ unsigned short f2bu(float x) {
    bf16 b = __float2bfloat16(x);
    return *reinterpret_cast<unsigned short*>(&b);
}
__device__ __forceinline__ float bu2f(unsigned short u) {
    return __uint_as_float(((unsigned)u) << 16);
}
__device__ __forceinline__ float bfe0(unsigned u) { return __uint_as_float(u << 16); }
__device__ __forceinline__ float bfe1(unsigned u) { return __uint_as_float(u & 0xffff0000u); }

union frag_u { unsigned short u[8]; bf16x8 v; };

// DPP-based add of a lane-shuffled copy (VALU pipe; no DS traffic).
template<int CTRL>
__device__ __forceinline__ float dpp_add(float x) {
    int y = __builtin_amdgcn_mov_dpp(__float_as_int(x), CTRL, 0xf, 0xf, true);
    return x + __int_as_float(y);
}
// Sum over each aligned 8-lane group: xor1 (quad_perm), xor2 (quad_perm),
// xor7 (row_half_mirror).  {1,2,7} spans the 3-bit group.
__device__ __forceinline__ float red8(float x) {
    x = dpp_add<0xB1>(x);    // quad_perm [1,0,3,2]  -> lane ^ 1
    x = dpp_add<0x4E>(x);    // quad_perm [2,3,0,1]  -> lane ^ 2
    x = dpp_add<0x141>(x);   // row_half_mirror      -> lane ^ 7
    return x;
}

// ---------------------------------------------------------------------------
// Kernel 0: lay W out in MFMA B-fragment order (hi/lo bf16 split) AND zero
// the per-node edge counters (replaces the hipMemsetAsync dispatch).
// ---------------------------------------------------------------------------
__global__ __launch_bounds__(256) void prep_kernel(
    const float* __restrict__ Wq, const float* __restrict__ Wk, const float* __restrict__ Wv,
    unsigned short* __restrict__ Wf, int* __restrict__ counts)
{
    int t = blockIdx.x * 256 + threadIdx.x;
    if (t < N_NODES) counts[t] = 0;
    if (t < 3 * 32 * 64) {
        int lane = t & 63;
        int ct   = (t >> 6) & 31;
        int mat  = t >> 11;
        const float* W = (mat == 0) ? Wq : (mat == 1) ? Wk : Wv;
        int c  = ct >> 3, tt = ct & 7;
        int n  = tt * 16 + (lane & 15);
        int kb = c * 32 + (lane >> 4) * 8;
        unsigned short* dst = Wf + (size_t)mat * 32768 + (size_t)ct * 1024 + (size_t)lane * 8;
#pragma unroll
        for (int j = 0; j < 8; ++j) {
            float w  = W[(size_t)(kb + j) * D + n];
            unsigned short hb = f2bu(w);
            float lo = w - bu2f(hb);
            dst[j]       = hb;          // hi (part 0)
            dst[512 + j] = f2bu(lo);    // lo (part 1)
        }
    }
}

// ---------------------------------------------------------------------------
// Kernel 1: fused Q/K/V projection via bf16 MFMA with hi/lo precision split.
// Also performs the edge histogram in its prologue (atomics hide under the
// A-fragment load + MFMA phases; removes a full 800k-thread dispatch).
// Q is stored row-major; K and V are stored PAIR-INTERLEAVED into one KV
// buffer: KV[n] is 512 B, position d (=lane) holds dword {k_2d,k_2d+1} at
// n*512+d*8 and dword {v_2d,v_2d+1} at +4 -> fused_node needs ONE dwordx2
// per edge per lane.
// ---------------------------------------------------------------------------
__global__ __launch_bounds__(256) void qkv_mfma(
    const float* __restrict__ E, const unsigned short* __restrict__ Wf,
    bf16* __restrict__ Q, char* __restrict__ KVb,
    const int* __restrict__ rows, int* __restrict__ counts)
{
    __shared__ unsigned short bsh[16384];   // 32 KB: B staging, then epilogue
    const int tid  = threadIdx.x;
    const int wave = tid >> 6;
    const int lane = tid & 63;
    const int r0w  = blockIdx.x * 128 + wave * 32;   // this wave's 32 rows

    // --- edge histogram slice: 4 edges/thread, 782*1024 >= 800000 ---
    {
        int e0 = (blockIdx.x * 256 + tid) * 4;
        if (e0 < N_EDGES) {
            int4 r4 = *reinterpret_cast<const int4*>(rows + e0);
            atomicAdd(&counts[r4.x], 1);
            atomicAdd(&counts[r4.y], 1);
            atomicAdd(&counts[r4.z], 1);
            atomicAdd(&counts[r4.w], 1);
        }
    }

    const int am = lane & 15;    // A row within 16-tile
    const int aq = lane >> 4;    // k quad

    // Load + split A fragments: 2 row-tiles x 4 k-chunks x 8 bf16 (hi/lo).
    frag_u ahi[2][4], alo[2][4];
#pragma unroll
    for (int rt = 0; rt < 2; ++rt) {
        int row = r0w + rt * 16 + am;
        if (row >= N_NODES) row = N_NODES - 1;     // clamp; stores are guarded
        const float* erow = E + (size_t)row * D + aq * 8;
#pragma unroll
        for (int c = 0; c < 4; ++c) {
            float4 e0 = *reinterpret_cast<const float4*>(erow + c * 32);
            float4 e1 = *reinterpret_cast<const float4*>(erow + c * 32 + 4);
            float ef[8] = {e0.x, e0.y, e0.z, e0.w, e1.x, e1.y, e1.z, e1.w};
#pragma unroll
            for (int j = 0; j < 8; ++j) {
                unsigned short hb = f2bu(ef[j]);
                ahi[rt][c].u[j] = hb;
                alo[rt][c].u[j] = f2bu(ef[j] - bu2f(hb));
            }
        }
    }

#pragma unroll
    for (int mat = 0; mat < 3; ++mat) {
        f32x4 acc[8][2];
#pragma unroll
        for (int t = 0; t < 8; ++t)
#pragma unroll
            for (int rt = 0; rt < 2; ++rt)
                acc[t][rt] = (f32x4){0.f, 0.f, 0.f, 0.f};

        const unsigned short* wm = Wf + (size_t)mat * 32768;

#pragma unroll
        for (int half = 0; half < 2; ++half) {
            __syncthreads();    // previous users of bsh are done
            // Stage 32 KB (c = 2*half .. 2*half+1): 2048 uint4, 8 per thread.
            const uint4* src = reinterpret_cast<const uint4*>(wm + half * 16384);
            uint4* dstv = reinterpret_cast<uint4*>(bsh);
#pragma unroll
            for (int k = 0; k < 8; ++k)
                dstv[k * 256 + tid] = src[k * 256 + tid];
            __syncthreads();

#pragma unroll
            for (int t = 0; t < 8; ++t) {
#pragma unroll
                for (int cc = 0; cc < 2; ++cc) {
                    const unsigned short* bp = bsh + (cc * 8 + t) * 1024 + lane * 8;
                    bf16x8 bhi = *reinterpret_cast<const bf16x8*>(bp);
                    bf16x8 blo = *reinterpret_cast<const bf16x8*>(bp + 512);
                    const int c = half * 2 + cc;
#pragma unroll
                    for (int rt = 0; rt < 2; ++rt) {
                        acc[t][rt] = __builtin_amdgcn_mfma_f32_16x16x32_bf16(alo[rt][c].v, bhi, acc[t][rt], 0, 0, 0);
                        acc[t][rt] = __builtin_amdgcn_mfma_f32_16x16x32_bf16(ahi[rt][c].v, blo, acc[t][rt], 0, 0, 0);
                        acc[t][rt] = __builtin_amdgcn_mfma_f32_16x16x32_bf16(ahi[rt][c].v, bhi, acc[t][rt], 0, 0, 0);
                    }
                }
            }
        }
        __syncthreads();   // all waves done reading B; bsh reusable per-wave

        // Epilogue: C-frags -> per-wave LDS slice (stride 136) -> global.
        // C layout: col = t*16+am, row = aq*4+r.
        unsigned short* ob = bsh + wave * 2176;   // 16 rows x 136
#pragma unroll
        for (int rt = 0; rt < 2; ++rt) {
#pragma unroll
            for (int t = 0; t < 8; ++t)
#pragma unroll
                for (int r = 0; r < 4; ++r)
                    ob[(aq * 4 + r) * 136 + t * 16 + am] = f2bu(acc[t][rt][r]);
            const int row = lane >> 2, c4 = lane & 3;
            int grow = r0w + rt * 16 + row;
            if (grow < N_NODES) {
                const uint4* srcb = reinterpret_cast<const uint4*>(ob + row * 136 + c4 * 32);
                if (mat == 0) {
                    uint4 d0 = srcb[0], d1 = srcb[1], d2 = srcb[2], d3 = srcb[3];
                    uint4* dst = reinterpret_cast<uint4*>(Q + (size_t)grow * D + c4 * 32);
                    dst[0] = d0; dst[1] = d1; dst[2] = d2; dst[3] = d3;
                } else {
                    // pair p = c4*16 + i*4 + q  ->  byte grow*512 + p*8 (+4 for V)
                    char* dstc = KVb + ((size_t)grow << 9) + (c4 << 7) + ((mat == 2) ? 4 : 0);
#pragma unroll
                    for (int i = 0; i < 4; ++i) {
                        uint4 dd = srcb[i];
                        *reinterpret_cast<unsigned*>(dstc + i * 32 + 0)  = dd.x;
                        *reinterpret_cast<unsigned*>(dstc + i * 32 + 8)  = dd.y;
                        *reinterpret_cast<unsigned*>(dstc + i * 32 + 16) = dd.z;
                        *reinterpret_cast<unsigned*>(dstc + i * 32 + 24) = dd.w;
                    }
                }
            }
        }
    }
}

// ---------------------------------------------------------------------------
// CSR build: 3-kernel exclusive scan -> scatter  (histogram now in qkv_mfma)
// ---------------------------------------------------------------------------
__global__ __launch_bounds__(256) void scan_block(
    const int* __restrict__ counts, int* __restrict__ scanned, int* __restrict__ block_sums)
{
    __shared__ int s[256];
    int tid = threadIdx.x;
    int i = blockIdx.x * 256 + tid;
    int v = (i < N_NODES) ? counts[i] : 0;
    s[tid] = v;
    __syncthreads();
#pragma unroll
    for (int off = 1; off < 256; off <<= 1) {
        int t = (tid >= off) ? s[tid - off] : 0;
        __syncthreads();
        s[tid] += t;
        __syncthreads();
    }
    if (i < N_NODES) scanned[i] = s[tid] - v;
    if (tid == 255) block_sums[blockIdx.x] = s[255];
}

__global__ __launch_bounds__(512) void scan_tops(int* __restrict__ block_sums)
{
    __shared__ int s[512];
    int tid = threadIdx.x;
    int v = (tid < NB) ? block_sums[tid] : 0;
    s[tid] = v;
    __syncthreads();
#pragma unroll
    for (int off = 1; off < 512; off <<= 1) {
        int t = (tid >= off) ? s[tid - off] : 0;
        __syncthreads();
        s[tid] += t;
        __syncthreads();
    }
    if (tid < NB) block_sums[tid] = s[tid] - v;
}

__global__ __launch_bounds__(256) void scan_add(
    int* __restrict__ scanned, const int* __restrict__ block_sums, int* __restrict__ cursor)
{
    int i = blockIdx.x * 256 + threadIdx.x;
    if (i < N_NODES) {
        int o = scanned[i] + block_sums[blockIdx.x];
        scanned[i] = o;
        cursor[i]  = o;
    }
}

__global__ __launch_bounds__(256) void scatter_kernel(
    const int* __restrict__ rows, const int* __restrict__ cols,
    int* __restrict__ cursor, int* __restrict__ csr_cols)
{
    int e = blockIdx.x * 256 + threadIdx.x;
    if (e < N_EDGES) {
        int pos = atomicAdd(&cursor[rows[e]], 1);
        csr_cols[pos] = cols[e];
    }
}

// ---------------------------------------------------------------------------
// Fused per-node attention + residual + LayerNorm. One wave per node.
//  - K/V pair-interleaved: one dwordx2 per edge per lane (32-bit voffset).
//  - 8-lane head reduction via 3 DPP v_add_f32 (no DS ops).
//  - Q pre-scaled by log2(e): softmax weight = v_exp(clip(p*log2e)).
//  - 4-edge unroll for 4 loads in flight.
// ---------------------------------------------------------------------------
__global__ __launch_bounds__(256) void fused_node(
    const bf16* __restrict__ Qb, const char* __restrict__ KVb,
    const int* __restrict__ offsets, const int* __restrict__ counts,
    const int* __restrict__ csr_cols,
    const float* __restrict__ emb,
    const float* __restrict__ gamma, const float* __restrict__ beta,
    float* __restrict__ out)
{
    int n = blockIdx.x * 4 + (threadIdx.x >> 6);     // grid covers exactly N_NODES
    int lane = threadIdx.x & 63;

    const float L2E   = 1.44269504f;
    const float CLIP2 = 14.4269504f;                 // 10 * log2(e)

    unsigned qu = *reinterpret_cast<const unsigned*>(Qb + (size_t)n * D + lane * 2);
    float q0 = bfe0(qu) * L2E, q1 = bfe1(qu) * L2E;

    int start = offsets[n];
    int cnt   = counts[n];
    unsigned lane8 = (unsigned)(lane << 3);

    float acc0 = 0.f, acc1 = 0.f, nrm = 0.f;
    for (int base = 0; base < cnt; base += 64) {
        int m = cnt - base; if (m > 64) m = 64;
        int moff = (base + lane < cnt) ? (csr_cols[start + base + lane] << 9) : 0;
        int j = 0;
        for (; j + 3 < m; j += 4) {
            int o0 = __shfl(moff, j,     64);
            int o1 = __shfl(moff, j + 1, 64);
            int o2 = __shfl(moff, j + 2, 64);
            int o3 = __shfl(moff, j + 3, 64);
            uint2 kv0 = *reinterpret_cast<const uint2*>(KVb + ((unsigned)o0 | lane8));
            uint2 kv1 = *reinterpret_cast<const uint2*>(KVb + ((unsigned)o1 | lane8));
            uint2 kv2 = *reinterpret_cast<const uint2*>(KVb + ((unsigned)o2 | lane8));
            uint2 kv3 = *reinterpret_cast<const uint2*>(KVb + ((unsigned)o3 | lane8));
            float p0 = q0 * bfe0(kv0.x) + q1 * bfe1(kv0.x);
            float p1 = q0 * bfe0(kv1.x) + q1 * bfe1(kv1.x);
            float p2 = q0 * bfe0(kv2.x) + q1 * bfe1(kv2.x);
            float p3 = q0 * bfe0(kv3.x) + q1 * bfe1(kv3.x);
            p0 = red8(p0); p1 = red8(p1); p2 = red8(p2); p3 = red8(p3);
            float s0 = __builtin_amdgcn_exp2f(fminf(fmaxf(p0, -CLIP2), CLIP2));
            float s1 = __builtin_amdgcn_exp2f(fminf(fmaxf(p1, -CLIP2), CLIP2));
            float s2 = __builtin_amdgcn_exp2f(fminf(fmaxf(p2, -CLIP2), CLIP2));
            float s3 = __builtin_amdgcn_exp2f(fminf(fmaxf(p3, -CLIP2), CLIP2));
            nrm  += (s0 + s1) + (s2 + s3);
            acc0 += s0 * bfe0(kv0.y); acc1 += s0 * bfe1(kv0.y);
            acc0 += s1 * bfe0(kv1.y); acc1 += s1 * bfe1(kv1.y);
            acc0 += s2 * bfe0(kv2.y); acc1 += s2 * bfe1(kv2.y);
            acc0 += s3 * bfe0(kv3.y); acc1 += s3 * bfe1(kv3.y);
        }
        for (; j < m; ++j) {
            int o0 = __shfl(moff, j, 64);
            uint2 kv0 = *reinterpret_cast<const uint2*>(KVb + ((unsigned)o0 | lane8));
            float p0 = red8(q0 * bfe0(kv0.x) + q1 * bfe1(kv0.x));
            float s0 = __builtin_amdgcn_exp2f(fminf(fmaxf(p0, -CLIP2), CLIP2));
            nrm  += s0;
            acc0 += s0 * bfe0(kv0.y);
            acc1 += s0 * bfe1(kv0.y);
        }
    }

    float w = 1.f / (nrm + 1e-8f);
    float2 e2 = *reinterpret_cast<const float2*>(emb + (size_t)n * D + lane * 2);
    float x0 = acc0 * w + e2.x;
    float x1 = acc1 * w + e2.y;

    float ssum = x0 + x1;
#pragma unroll
    for (int off = 32; off; off >>= 1) ssum += __shfl_xor(ssum, off, 64);
    float mean = ssum * (1.0f / 128.0f);
    float d0 = x0 - mean, d1 = x1 - mean;
    float var = d0 * d0 + d1 * d1;
#pragma unroll
    for (int off = 32; off; off >>= 1) var += __shfl_xor(var, off, 64);
    float rs = rsqrtf(var * (1.0f / 128.0f) + 1e-6f);

    float2 g2 = *reinterpret_cast<const float2*>(gamma + lane * 2);
    float2 b2 = *reinterpret_cast<const float2*>(beta + lane * 2);
    float2 o2 = make_float2(d0 * rs * g2.x + b2.x, d1 * rs * g2.y + b2.y);
    *reinterpret_cast<float2*>(out + (size_t)n * D + lane * 2) = o2;
}

// ---------------------------------------------------------------------------
extern "C" void kernel_launch(void* const* d_in, const int* in_sizes, int n_in,
                              void* d_out, int out_size, void* d_ws, size_t ws_size,
                              hipStream_t stream)
{
    const float* emb   = (const float*)d_in[0];
    const float* qW    = (const float*)d_in[1];
    const float* kW    = (const float*)d_in[2];
    const float* vW    = (const float*)d_in[3];
    const float* gamma = (const float*)d_in[4];
    const float* beta  = (const float*)d_in[5];
    const int*   eidx  = (const int*)d_in[6];
    const int*   rows  = eidx;
    const int*   cols  = eidx + N_EDGES;
    float* out = (float*)d_out;

    const size_t ND = (size_t)N_NODES * D;
    bf16* Qb  = (bf16*)d_ws;
    char* KVb = (char*)(Qb + ND);                    // N_NODES * 512 B (K/V interleaved)
    int* counts     = (int*)(KVb + (size_t)N_NODES * 512);
    int* offsets    = counts + N_NODES;
    int* cursor     = offsets + N_NODES;
    int* block_sums = cursor + N_NODES;
    int* csr_cols   = block_sums + 512;
    unsigned short* Wf = (unsigned short*)(csr_cols + N_EDGES);  // 3*32768 ushort

    prep_kernel<<<NB, 256, 0, stream>>>(qW, kW, vW, Wf, counts);
    qkv_mfma<<<(N_NODES + 127) / 128, 256, 0, stream>>>(emb, Wf, Qb, KVb, rows, counts);

    scan_block<<<NB, 256, 0, stream>>>(counts, offsets, block_sums);
    scan_tops<<<1, 512, 0, stream>>>(block_sums);
    scan_add<<<NB, 256, 0, stream>>>(offsets, block_sums, cursor);
    scatter_kernel<<<(N_EDGES + 255) / 256, 256, 0, stream>>>(rows, cols, cursor, csr_cols);

    fused_node<<<(N_NODES + 3) / 4, 256, 0, stream>>>(
        Qb, KVb, offsets, counts, csr_cols, emb, gamma, beta, out);
}

// Round 2
// 296.443 us; speedup vs baseline: 1.1455x; 1.1455x over previous
//
#include <hip/hip_runtime.h>
#include <hip/hip_bf16.h>

#define N_NODES 100000
#define N_EDGES 800000
#define D 128
#define NH 8
#define NB ((N_NODES + 255) / 256)   // 391 scan blocks

typedef __hip_bfloat16 bf16;
typedef __bf16 bf16x8 __attribute__((ext_vector_type(8)));
typedef float  f32x4  __attribute__((ext_vector_type(4)));

__device__ __forceinline__ unsigned short f2bu(float x) {
    bf16 b = __float2bfloat16(x);
    return *reinterpret_cast<unsigned short*>(&b);
}
__device__ __forceinline__ float bu2f(unsigned short u) {
    return __uint_as_float(((unsigned)u) << 16);
}
__device__ __forceinline__ float bfe0(unsigned u) { return __uint_as_float(u << 16); }
__device__ __forceinline__ float bfe1(unsigned u) { return __uint_as_float(u & 0xffff0000u); }

union frag_u { unsigned short u[8]; bf16x8 v; };

// DPP-based add of a lane-shuffled copy (VALU pipe; no DS traffic).
template<int CTRL>
__device__ __forceinline__ float dpp_add(float x) {
    int y = __builtin_amdgcn_mov_dpp(__float_as_int(x), CTRL, 0xf, 0xf, true);
    return x + __int_as_float(y);
}
// Sum over each aligned 8-lane group: xor1 (quad_perm), xor2 (quad_perm),
// xor7 (row_half_mirror).  {1,2,7} spans the 3-bit group.
__device__ __forceinline__ float red8(float x) {
    x = dpp_add<0xB1>(x);    // quad_perm [1,0,3,2]  -> lane ^ 1
    x = dpp_add<0x4E>(x);    // quad_perm [2,3,0,1]  -> lane ^ 2
    x = dpp_add<0x141>(x);   // row_half_mirror      -> lane ^ 7
    return x;
}

// ---------------------------------------------------------------------------
// Kernel 0: lay W out in MFMA B-fragment order (hi/lo bf16 split) AND zero
// the per-node edge counters (replaces the hipMemsetAsync dispatch).
// Matrix 0 = Q (Wq cols 0..127 as-is).
// Matrices 1,2 = "KV-low"/"KV-high": column n of half m sources
//   g = m*128 + n;  W = (g&2) ? Wv : Wk;  col = 2*(g>>2) + (g&1)
// so the MFMA output row IS the fused dword-interleaved KV layout
// ({k_2d,k_2d+1} at byte d*8, {v_2d,v_2d+1} at +4) and the epilogue can
// store contiguous uint4s exactly like the Q path (coalesced, no partial
// sectors).  This undoes round-1's 2.2x write amplification for free.
// ---------------------------------------------------------------------------
__global__ __launch_bounds__(256) void prep_kernel(
    const float* __restrict__ Wq, const float* __restrict__ Wk, const float* __restrict__ Wv,
    unsigned short* __restrict__ Wf, int* __restrict__ counts)
{
    int t = blockIdx.x * 256 + threadIdx.x;
    if (t < N_NODES) counts[t] = 0;
    if (t < 3 * 32 * 64) {
        int lane = t & 63;
        int ct   = (t >> 6) & 31;
        int mat  = t >> 11;
        int c  = ct >> 3, tt = ct & 7;
        int n  = tt * 16 + (lane & 15);
        int kb = c * 32 + (lane >> 4) * 8;
        const float* W;
        int col;
        if (mat == 0) {
            W = Wq; col = n;
        } else {
            int g = (mat - 1) * 128 + n;
            W = (g & 2) ? Wv : Wk;
            col = ((g >> 2) << 1) | (g & 1);
        }
        unsigned short* dst = Wf + (size_t)mat * 32768 + (size_t)ct * 1024 + (size_t)lane * 8;
#pragma unroll
        for (int j = 0; j < 8; ++j) {
            float w  = W[(size_t)(kb + j) * D + col];
            unsigned short hb = f2bu(w);
            float lo = w - bu2f(hb);
            dst[j]       = hb;          // hi (part 0)
            dst[512 + j] = f2bu(lo);    // lo (part 1)
        }
    }
}

// ---------------------------------------------------------------------------
// Kernel 1: fused Q/KV projection via bf16 MFMA with hi/lo precision split.
// Edge histogram fused into the prologue (atomics hide under MFMA phases).
// All three output halves (Q, KV-low, KV-high) store contiguous coalesced
// dwordx4 rows; KV halves land at KVb + row*512 + m*256.
// ---------------------------------------------------------------------------
__global__ __launch_bounds__(256) void qkv_mfma(
    const float* __restrict__ E, const unsigned short* __restrict__ Wf,
    bf16* __restrict__ Q, char* __restrict__ KVb,
    const int* __restrict__ rows, int* __restrict__ counts)
{
    __shared__ unsigned short bsh[16384];   // 32 KB: B staging, then epilogue
    const int tid  = threadIdx.x;
    const int wave = tid >> 6;
    const int lane = tid & 63;
    const int r0w  = blockIdx.x * 128 + wave * 32;   // this wave's 32 rows

    // --- edge histogram slice: 4 edges/thread, 782*1024 >= 800000 ---
    {
        int e0 = (blockIdx.x * 256 + tid) * 4;
        if (e0 < N_EDGES) {
            int4 r4 = *reinterpret_cast<const int4*>(rows + e0);
            atomicAdd(&counts[r4.x], 1);
            atomicAdd(&counts[r4.y], 1);
            atomicAdd(&counts[r4.z], 1);
            atomicAdd(&counts[r4.w], 1);
        }
    }

    const int am = lane & 15;    // A row within 16-tile
    const int aq = lane >> 4;    // k quad

    // Load + split A fragments: 2 row-tiles x 4 k-chunks x 8 bf16 (hi/lo).
    frag_u ahi[2][4], alo[2][4];
#pragma unroll
    for (int rt = 0; rt < 2; ++rt) {
        int row = r0w + rt * 16 + am;
        if (row >= N_NODES) row = N_NODES - 1;     // clamp; stores are guarded
        const float* erow = E + (size_t)row * D + aq * 8;
#pragma unroll
        for (int c = 0; c < 4; ++c) {
            float4 e0 = *reinterpret_cast<const float4*>(erow + c * 32);
            float4 e1 = *reinterpret_cast<const float4*>(erow + c * 32 + 4);
            float ef[8] = {e0.x, e0.y, e0.z, e0.w, e1.x, e1.y, e1.z, e1.w};
#pragma unroll
            for (int j = 0; j < 8; ++j) {
                unsigned short hb = f2bu(ef[j]);
                ahi[rt][c].u[j] = hb;
                alo[rt][c].u[j] = f2bu(ef[j] - bu2f(hb));
            }
        }
    }

#pragma unroll
    for (int mat = 0; mat < 3; ++mat) {
        f32x4 acc[8][2];
#pragma unroll
        for (int t = 0; t < 8; ++t)
#pragma unroll
            for (int rt = 0; rt < 2; ++rt)
                acc[t][rt] = (f32x4){0.f, 0.f, 0.f, 0.f};

        const unsigned short* wm = Wf + (size_t)mat * 32768;

#pragma unroll
        for (int half = 0; half < 2; ++half) {
            __syncthreads();    // previous users of bsh are done
            // Stage 32 KB (c = 2*half .. 2*half+1): 2048 uint4, 8 per thread.
            const uint4* src = reinterpret_cast<const uint4*>(wm + half * 16384);
            uint4* dstv = reinterpret_cast<uint4*>(bsh);
#pragma unroll
            for (int k = 0; k < 8; ++k)
                dstv[k * 256 + tid] = src[k * 256 + tid];
            __syncthreads();

#pragma unroll
            for (int t = 0; t < 8; ++t) {
#pragma unroll
                for (int cc = 0; cc < 2; ++cc) {
                    const unsigned short* bp = bsh + (cc * 8 + t) * 1024 + lane * 8;
                    bf16x8 bhi = *reinterpret_cast<const bf16x8*>(bp);
                    bf16x8 blo = *reinterpret_cast<const bf16x8*>(bp + 512);
                    const int c = half * 2 + cc;
#pragma unroll
                    for (int rt = 0; rt < 2; ++rt) {
                        acc[t][rt] = __builtin_amdgcn_mfma_f32_16x16x32_bf16(alo[rt][c].v, bhi, acc[t][rt], 0, 0, 0);
                        acc[t][rt] = __builtin_amdgcn_mfma_f32_16x16x32_bf16(ahi[rt][c].v, blo, acc[t][rt], 0, 0, 0);
                        acc[t][rt] = __builtin_amdgcn_mfma_f32_16x16x32_bf16(ahi[rt][c].v, bhi, acc[t][rt], 0, 0, 0);
                    }
                }
            }
        }
        __syncthreads();   // all waves done reading B; bsh reusable per-wave

        // Epilogue: C-frags -> per-wave LDS slice (stride 136) -> coalesced
        // dwordx4 stores.  C layout: col = t*16+am, row = aq*4+r.
        unsigned short* ob = bsh + wave * 2176;   // 16 rows x 136
#pragma unroll
        for (int rt = 0; rt < 2; ++rt) {
#pragma unroll
            for (int t = 0; t < 8; ++t)
#pragma unroll
                for (int r = 0; r < 4; ++r)
                    ob[(aq * 4 + r) * 136 + t * 16 + am] = f2bu(acc[t][rt][r]);
            const int row = lane >> 2, c4 = lane & 3;
            int grow = r0w + rt * 16 + row;
            if (grow < N_NODES) {
                const uint4* srcb = reinterpret_cast<const uint4*>(ob + row * 136 + c4 * 32);
                uint4 d0 = srcb[0], d1 = srcb[1], d2 = srcb[2], d3 = srcb[3];
                uint4* dst;
                if (mat == 0)
                    dst = reinterpret_cast<uint4*>(Q + (size_t)grow * D + c4 * 32);
                else
                    dst = reinterpret_cast<uint4*>(KVb + ((size_t)grow << 9)
                                                   + (size_t)(mat - 1) * 256 + (size_t)c4 * 64);
                dst[0] = d0; dst[1] = d1; dst[2] = d2; dst[3] = d3;
            }
        }
    }
}

// ---------------------------------------------------------------------------
// CSR build: 3-kernel exclusive scan -> scatter  (histogram in qkv_mfma)
// ---------------------------------------------------------------------------
__global__ __launch_bounds__(256) void scan_block(
    const int* __restrict__ counts, int* __restrict__ scanned, int* __restrict__ block_sums)
{
    __shared__ int s[256];
    int tid = threadIdx.x;
    int i = blockIdx.x * 256 + tid;
    int v = (i < N_NODES) ? counts[i] : 0;
    s[tid] = v;
    __syncthreads();
#pragma unroll
    for (int off = 1; off < 256; off <<= 1) {
        int t = (tid >= off) ? s[tid - off] : 0;
        __syncthreads();
        s[tid] += t;
        __syncthreads();
    }
    if (i < N_NODES) scanned[i] = s[tid] - v;
    if (tid == 255) block_sums[blockIdx.x] = s[255];
}

__global__ __launch_bounds__(512) void scan_tops(int* __restrict__ block_sums)
{
    __shared__ int s[512];
    int tid = threadIdx.x;
    int v = (tid < NB) ? block_sums[tid] : 0;
    s[tid] = v;
    __syncthreads();
#pragma unroll
    for (int off = 1; off < 512; off <<= 1) {
        int t = (tid >= off) ? s[tid - off] : 0;
        __syncthreads();
        s[tid] += t;
        __syncthreads();
    }
    if (tid < NB) block_sums[tid] = s[tid] - v;
}

__global__ __launch_bounds__(256) void scan_add(
    int* __restrict__ scanned, const int* __restrict__ block_sums, int* __restrict__ cursor)
{
    int i = blockIdx.x * 256 + threadIdx.x;
    if (i < N_NODES) {
        int o = scanned[i] + block_sums[blockIdx.x];
        scanned[i] = o;
        cursor[i]  = o;
    }
}

__global__ __launch_bounds__(256) void scatter_kernel(
    const int* __restrict__ rows, const int* __restrict__ cols,
    int* __restrict__ cursor, int* __restrict__ csr_cols)
{
    int e = blockIdx.x * 256 + threadIdx.x;
    if (e < N_EDGES) {
        int pos = atomicAdd(&cursor[rows[e]], 1);
        csr_cols[pos] = cols[e];
    }
}

// ---------------------------------------------------------------------------
// Fused per-node attention + residual + LayerNorm. One wave per node.
//  - K/V pair-interleaved: one dwordx2 per edge per lane (32-bit voffset).
//  - 8-lane head reduction via 3 DPP v_add_f32 (no DS ops).
//  - Q pre-scaled by log2(e): softmax weight = v_exp(clip(p*log2e)).
//  - 4-edge unroll for 4 loads in flight.   (unchanged this round)
// ---------------------------------------------------------------------------
__global__ __launch_bounds__(256) void fused_node(
    const bf16* __restrict__ Qb, const char* __restrict__ KVb,
    const int* __restrict__ offsets, const int* __restrict__ counts,
    const int* __restrict__ csr_cols,
    const float* __restrict__ emb,
    const float* __restrict__ gamma, const float* __restrict__ beta,
    float* __restrict__ out)
{
    int n = blockIdx.x * 4 + (threadIdx.x >> 6);     // grid covers exactly N_NODES
    int lane = threadIdx.x & 63;

    const float L2E   = 1.44269504f;
    const float CLIP2 = 14.4269504f;                 // 10 * log2(e)

    unsigned qu = *reinterpret_cast<const unsigned*>(Qb + (size_t)n * D + lane * 2);
    float q0 = bfe0(qu) * L2E, q1 = bfe1(qu) * L2E;

    int start = offsets[n];
    int cnt   = counts[n];
    unsigned lane8 = (unsigned)(lane << 3);

    float acc0 = 0.f, acc1 = 0.f, nrm = 0.f;
    for (int base = 0; base < cnt; base += 64) {
        int m = cnt - base; if (m > 64) m = 64;
        int moff = (base + lane < cnt) ? (csr_cols[start + base + lane] << 9) : 0;
        int j = 0;
        for (; j + 3 < m; j += 4) {
            int o0 = __shfl(moff, j,     64);
            int o1 = __shfl(moff, j + 1, 64);
            int o2 = __shfl(moff, j + 2, 64);
            int o3 = __shfl(moff, j + 3, 64);
            uint2 kv0 = *reinterpret_cast<const uint2*>(KVb + ((unsigned)o0 | lane8));
            uint2 kv1 = *reinterpret_cast<const uint2*>(KVb + ((unsigned)o1 | lane8));
            uint2 kv2 = *reinterpret_cast<const uint2*>(KVb + ((unsigned)o2 | lane8));
            uint2 kv3 = *reinterpret_cast<const uint2*>(KVb + ((unsigned)o3 | lane8));
            float p0 = q0 * bfe0(kv0.x) + q1 * bfe1(kv0.x);
            float p1 = q0 * bfe0(kv1.x) + q1 * bfe1(kv1.x);
            float p2 = q0 * bfe0(kv2.x) + q1 * bfe1(kv2.x);
            float p3 = q0 * bfe0(kv3.x) + q1 * bfe1(kv3.x);
            p0 = red8(p0); p1 = red8(p1); p2 = red8(p2); p3 = red8(p3);
            float s0 = __builtin_amdgcn_exp2f(fminf(fmaxf(p0, -CLIP2), CLIP2));
            float s1 = __builtin_amdgcn_exp2f(fminf(fmaxf(p1, -CLIP2), CLIP2));
            float s2 = __builtin_amdgcn_exp2f(fminf(fmaxf(p2, -CLIP2), CLIP2));
            float s3 = __builtin_amdgcn_exp2f(fminf(fmaxf(p3, -CLIP2), CLIP2));
            nrm  += (s0 + s1) + (s2 + s3);
            acc0 += s0 * bfe0(kv0.y); acc1 += s0 * bfe1(kv0.y);
            acc0 += s1 * bfe0(kv1.y); acc1 += s1 * bfe1(kv1.y);
            acc0 += s2 * bfe0(kv2.y); acc1 += s2 * bfe1(kv2.y);
            acc0 += s3 * bfe0(kv3.y); acc1 += s3 * bfe1(kv3.y);
        }
        for (; j < m; ++j) {
            int o0 = __shfl(moff, j, 64);
            uint2 kv0 = *reinterpret_cast<const uint2*>(KVb + ((unsigned)o0 | lane8));
            float p0 = red8(q0 * bfe0(kv0.x) + q1 * bfe1(kv0.x));
            float s0 = __builtin_amdgcn_exp2f(fminf(fmaxf(p0, -CLIP2), CLIP2));
            nrm  += s0;
            acc0 += s0 * bfe0(kv0.y);
            acc1 += s0 * bfe1(kv0.y);
        }
    }

    float w = 1.f / (nrm + 1e-8f);
    float2 e2 = *reinterpret_cast<const float2*>(emb + (size_t)n * D + lane * 2);
    float x0 = acc0 * w + e2.x;
    float x1 = acc1 * w + e2.y;

    float ssum = x0 + x1;
#pragma unroll
    for (int off = 32; off; off >>= 1) ssum += __shfl_xor(ssum, off, 64);
    float mean = ssum * (1.0f / 128.0f);
    float d0 = x0 - mean, d1 = x1 - mean;
    float var = d0 * d0 + d1 * d1;
#pragma unroll
    for (int off = 32; off; off >>= 1) var += __shfl_xor(var, off, 64);
    float rs = rsqrtf(var * (1.0f / 128.0f) + 1e-6f);

    float2 g2 = *reinterpret_cast<const float2*>(gamma + lane * 2);
    float2 b2 = *reinterpret_cast<const float2*>(beta + lane * 2);
    float2 o2 = make_float2(d0 * rs * g2.x + b2.x, d1 * rs * g2.y + b2.y);
    *reinterpret_cast<float2*>(out + (size_t)n * D + lane * 2) = o2;
}

// ---------------------------------------------------------------------------
extern "C" void kernel_launch(void* const* d_in, const int* in_sizes, int n_in,
                              void* d_out, int out_size, void* d_ws, size_t ws_size,
                              hipStream_t stream)
{
    const float* emb   = (const float*)d_in[0];
    const float* qW    = (const float*)d_in[1];
    const float* kW    = (const float*)d_in[2];
    const float* vW    = (const float*)d_in[3];
    const float* gamma = (const float*)d_in[4];
    const float* beta  = (const float*)d_in[5];
    const int*   eidx  = (const int*)d_in[6];
    const int*   rows  = eidx;
    const int*   cols  = eidx + N_EDGES;
    float* out = (float*)d_out;

    const size_t ND = (size_t)N_NODES * D;
    bf16* Qb  = (bf16*)d_ws;
    char* KVb = (char*)(Qb + ND);                    // N_NODES * 512 B (K/V interleaved)
    int* counts     = (int*)(KVb + (size_t)N_NODES * 512);
    int* offsets    = counts + N_NODES;
    int* cursor     = offsets + N_NODES;
    int* block_sums = cursor + N_NODES;
    int* csr_cols   = block_sums + 512;
    unsigned short* Wf = (unsigned short*)(csr_cols + N_EDGES);  // 3*32768 ushort

    prep_kernel<<<NB, 256, 0, stream>>>(qW, kW, vW, Wf, counts);
    qkv_mfma<<<(N_NODES + 127) / 128, 256, 0, stream>>>(emb, Wf, Qb, KVb, rows, counts);

    scan_block<<<NB, 256, 0, stream>>>(counts, offsets, block_sums);
    scan_tops<<<1, 512, 0, stream>>>(block_sums);
    scan_add<<<NB, 256, 0, stream>>>(offsets, block_sums, cursor);
    scatter_kernel<<<(N_EDGES + 255) / 256, 256, 0, stream>>>(rows, cols, cursor, csr_cols);

    fused_node<<<(N_NODES + 3) / 4, 256, 0, stream>>>(
        Qb, KVb, offsets, counts, csr_cols, emb, gamma, beta, out);
}

// Round 3
// 285.205 us; speedup vs baseline: 1.1907x; 1.0394x over previous
//
#include <hip/hip_runtime.h>
#include <hip/hip_bf16.h>

#define N_NODES 100000
#define N_EDGES 800000
#define D 128
#define NH 8
#define NB ((N_NODES + 255) / 256)   // 391 scan blocks
#define NBQ ((N_NODES + 63) / 64)    // 1563 qkv blocks (64 rows each)

typedef __hip_bfloat16 bf16;
typedef __bf16 bf16x8 __attribute__((ext_vector_type(8)));
typedef float  f32x4  __attribute__((ext_vector_type(4)));

__device__ __forceinline__ unsigned short f2bu(float x) {
    bf16 b = __float2bfloat16(x);
    return *reinterpret_cast<unsigned short*>(&b);
}
__device__ __forceinline__ float bu2f(unsigned short u) {
    return __uint_as_float(((unsigned)u) << 16);
}
__device__ __forceinline__ float bfe0(unsigned u) { return __uint_as_float(u << 16); }
__device__ __forceinline__ float bfe1(unsigned u) { return __uint_as_float(u & 0xffff0000u); }

union frag_u { unsigned short u[8]; bf16x8 v; };

// DPP-based add of a lane-shuffled copy (VALU pipe; no DS traffic).
template<int CTRL>
__device__ __forceinline__ float dpp_add(float x) {
    int y = __builtin_amdgcn_mov_dpp(__float_as_int(x), CTRL, 0xf, 0xf, true);
    return x + __int_as_float(y);
}
// Sum over each aligned 8-lane group: xor1, xor2, xor7 spans the 3-bit group.
__device__ __forceinline__ float red8(float x) {
    x = dpp_add<0xB1>(x);    // quad_perm [1,0,3,2]  -> lane ^ 1
    x = dpp_add<0x4E>(x);    // quad_perm [2,3,0,1]  -> lane ^ 2
    x = dpp_add<0x141>(x);   // row_half_mirror      -> lane ^ 7
    return x;
}

// ---------------------------------------------------------------------------
// Kernel 0: lay W out in MFMA B-fragment order (hi/lo bf16 split) AND zero
// the per-node edge counters.  Matrix 0 = Q.  Matrices 1,2 = KV-low/KV-high
// with columns permuted so the MFMA output row IS the fused dword-interleaved
// KV layout ({k_2d,k_2d+1} at byte d*8, {v_2d,v_2d+1} at +4)  ->  epilogue
// stores stay contiguous/coalesced.
// ---------------------------------------------------------------------------
__global__ __launch_bounds__(256) void prep_kernel(
    const float* __restrict__ Wq, const float* __restrict__ Wk, const float* __restrict__ Wv,
    unsigned short* __restrict__ Wf, int* __restrict__ counts)
{
    int t = blockIdx.x * 256 + threadIdx.x;
    if (t < N_NODES) counts[t] = 0;
    if (t < 3 * 32 * 64) {
        int lane = t & 63;
        int ct   = (t >> 6) & 31;
        int mat  = t >> 11;
        int c  = ct >> 3, tt = ct & 7;
        int n  = tt * 16 + (lane & 15);
        int kb = c * 32 + (lane >> 4) * 8;
        const float* W;
        int col;
        if (mat == 0) {
            W = Wq; col = n;
        } else {
            int g = (mat - 1) * 128 + n;
            W = (g & 2) ? Wv : Wk;
            col = ((g >> 2) << 1) | (g & 1);
        }
        unsigned short* dst = Wf + (size_t)mat * 32768 + (size_t)ct * 1024 + (size_t)lane * 8;
#pragma unroll
        for (int j = 0; j < 8; ++j) {
            float w  = W[(size_t)(kb + j) * D + col];
            unsigned short hb = f2bu(w);
            float lo = w - bu2f(hb);
            dst[j]       = hb;          // hi (part 0)
            dst[512 + j] = f2bu(lo);    // lo (part 1)
        }
    }
}

// ---------------------------------------------------------------------------
// Kernel 1: fused Q/KV projection via bf16 MFMA with hi/lo precision split.
// Geometry this round: 64 rows/block, 16 rows/wave (was 128/32).  1563
// blocks ~= 6/CU; 32 KB LDS caps residency at 5 blocks/CU = 20 waves/CU, so
// one block's staging/barrier stalls hide under four other blocks' MFMA.
// Edge histogram fused into the prologue (2 edges/thread at this grid).
// ---------------------------------------------------------------------------
__global__ __launch_bounds__(256) void qkv_mfma(
    const float* __restrict__ E, const unsigned short* __restrict__ Wf,
    bf16* __restrict__ Q, char* __restrict__ KVb,
    const int* __restrict__ rows, int* __restrict__ counts)
{
    __shared__ unsigned short bsh[16384];   // 32 KB: B staging, then epilogue
    const int tid  = threadIdx.x;
    const int wave = tid >> 6;
    const int lane = tid & 63;
    const int r0w  = blockIdx.x * 64 + wave * 16;   // this wave's 16 rows

    // --- edge histogram slice: 2 edges/thread, 1563*512 >= 800000 ---
    {
        int e0 = (blockIdx.x * 256 + tid) * 2;
        if (e0 < N_EDGES) {
            int2 r2 = *reinterpret_cast<const int2*>(rows + e0);
            atomicAdd(&counts[r2.x], 1);
            atomicAdd(&counts[r2.y], 1);
        }
    }

    const int am = lane & 15;    // A row within 16-tile
    const int aq = lane >> 4;    // k quad

    // Load + split A fragments: 4 k-chunks x 8 bf16 (hi/lo).
    frag_u ahi[4], alo[4];
    {
        int row = r0w + am;
        if (row >= N_NODES) row = N_NODES - 1;     // clamp; stores are guarded
        const float* erow = E + (size_t)row * D + aq * 8;
#pragma unroll
        for (int c = 0; c < 4; ++c) {
            float4 e0 = *reinterpret_cast<const float4*>(erow + c * 32);
            float4 e1 = *reinterpret_cast<const float4*>(erow + c * 32 + 4);
            float ef[8] = {e0.x, e0.y, e0.z, e0.w, e1.x, e1.y, e1.z, e1.w};
#pragma unroll
            for (int j = 0; j < 8; ++j) {
                unsigned short hb = f2bu(ef[j]);
                ahi[c].u[j] = hb;
                alo[c].u[j] = f2bu(ef[j] - bu2f(hb));
            }
        }
    }

#pragma unroll
    for (int mat = 0; mat < 3; ++mat) {
        f32x4 acc[8];
#pragma unroll
        for (int t = 0; t < 8; ++t)
            acc[t] = (f32x4){0.f, 0.f, 0.f, 0.f};

        const unsigned short* wm = Wf + (size_t)mat * 32768;

#pragma unroll
        for (int half = 0; half < 2; ++half) {
            __syncthreads();    // previous users of bsh are done
            // Stage 32 KB (c = 2*half .. 2*half+1): 2048 uint4, 8 per thread.
            const uint4* src = reinterpret_cast<const uint4*>(wm + half * 16384);
            uint4* dstv = reinterpret_cast<uint4*>(bsh);
#pragma unroll
            for (int k = 0; k < 8; ++k)
                dstv[k * 256 + tid] = src[k * 256 + tid];
            __syncthreads();

#pragma unroll
            for (int t = 0; t < 8; ++t) {
#pragma unroll
                for (int cc = 0; cc < 2; ++cc) {
                    const unsigned short* bp = bsh + (cc * 8 + t) * 1024 + lane * 8;
                    bf16x8 bhi = *reinterpret_cast<const bf16x8*>(bp);
                    bf16x8 blo = *reinterpret_cast<const bf16x8*>(bp + 512);
                    const int c = half * 2 + cc;
                    acc[t] = __builtin_amdgcn_mfma_f32_16x16x32_bf16(alo[c].v, bhi, acc[t], 0, 0, 0);
                    acc[t] = __builtin_amdgcn_mfma_f32_16x16x32_bf16(ahi[c].v, blo, acc[t], 0, 0, 0);
                    acc[t] = __builtin_amdgcn_mfma_f32_16x16x32_bf16(ahi[c].v, bhi, acc[t], 0, 0, 0);
                }
            }
        }
        __syncthreads();   // all waves done reading B; bsh reusable per-wave

        // Epilogue: C-frags -> per-wave LDS slice (stride 136) -> coalesced
        // dwordx4 stores.  C layout: col = t*16+am, row = aq*4+r.
        unsigned short* ob = bsh + wave * 2176;   // 16 rows x 136
#pragma unroll
        for (int t = 0; t < 8; ++t)
#pragma unroll
            for (int r = 0; r < 4; ++r)
                ob[(aq * 4 + r) * 136 + t * 16 + am] = f2bu(acc[t][r]);
        {
            const int row = lane >> 2, c4 = lane & 3;
            int grow = r0w + row;
            if (grow < N_NODES) {
                const uint4* srcb = reinterpret_cast<const uint4*>(ob + row * 136 + c4 * 32);
                uint4 d0 = srcb[0], d1 = srcb[1], d2 = srcb[2], d3 = srcb[3];
                uint4* dst;
                if (mat == 0)
                    dst = reinterpret_cast<uint4*>(Q + (size_t)grow * D + c4 * 32);
                else
                    dst = reinterpret_cast<uint4*>(KVb + ((size_t)grow << 9)
                                                   + (size_t)(mat - 1) * 256 + (size_t)c4 * 64);
                dst[0] = d0; dst[1] = d1; dst[2] = d2; dst[3] = d3;
            }
        }
    }
}

// ---------------------------------------------------------------------------
// CSR build: 3-kernel exclusive scan -> scatter  (histogram in qkv_mfma)
// ---------------------------------------------------------------------------
__global__ __launch_bounds__(256) void scan_block(
    const int* __restrict__ counts, int* __restrict__ scanned, int* __restrict__ block_sums)
{
    __shared__ int s[256];
    int tid = threadIdx.x;
    int i = blockIdx.x * 256 + tid;
    int v = (i < N_NODES) ? counts[i] : 0;
    s[tid] = v;
    __syncthreads();
#pragma unroll
    for (int off = 1; off < 256; off <<= 1) {
        int t = (tid >= off) ? s[tid - off] : 0;
        __syncthreads();
        s[tid] += t;
        __syncthreads();
    }
    if (i < N_NODES) scanned[i] = s[tid] - v;
    if (tid == 255) block_sums[blockIdx.x] = s[255];
}

__global__ __launch_bounds__(512) void scan_tops(int* __restrict__ block_sums)
{
    __shared__ int s[512];
    int tid = threadIdx.x;
    int v = (tid < NB) ? block_sums[tid] : 0;
    s[tid] = v;
    __syncthreads();
#pragma unroll
    for (int off = 1; off < 512; off <<= 1) {
        int t = (tid >= off) ? s[tid - off] : 0;
        __syncthreads();
        s[tid] += t;
        __syncthreads();
    }
    if (tid < NB) block_sums[tid] = s[tid] - v;
}

__global__ __launch_bounds__(256) void scan_add(
    int* __restrict__ scanned, const int* __restrict__ block_sums, int* __restrict__ cursor)
{
    int i = blockIdx.x * 256 + threadIdx.x;
    if (i < N_NODES) {
        int o = scanned[i] + block_sums[blockIdx.x];
        scanned[i] = o;
        cursor[i]  = o;
    }
}

__global__ __launch_bounds__(256) void scatter_kernel(
    const int* __restrict__ rows, const int* __restrict__ cols,
    int* __restrict__ cursor, int* __restrict__ csr_cols)
{
    int e = blockIdx.x * 256 + threadIdx.x;
    if (e < N_EDGES) {
        int pos = atomicAdd(&cursor[rows[e]], 1);
        csr_cols[pos] = cols[e];
    }
}

// ---------------------------------------------------------------------------
// Fused per-node attention + residual + LayerNorm. One wave per node.
//  - K/V pair-interleaved: one dwordx2 per edge per lane (32-bit voffset).
//  - 8-lane head reduction via 3 DPP v_add_f32 (no DS ops).
//  - Q pre-scaled by log2(e): softmax weight = v_exp(clip(p*log2e)).
//  - 4-edge unroll for 4 loads in flight.   (unchanged this round)
// ---------------------------------------------------------------------------
__global__ __launch_bounds__(256) void fused_node(
    const bf16* __restrict__ Qb, const char* __restrict__ KVb,
    const int* __restrict__ offsets, const int* __restrict__ counts,
    const int* __restrict__ csr_cols,
    const float* __restrict__ emb,
    const float* __restrict__ gamma, const float* __restrict__ beta,
    float* __restrict__ out)
{
    int n = blockIdx.x * 4 + (threadIdx.x >> 6);     // grid covers exactly N_NODES
    int lane = threadIdx.x & 63;

    const float L2E   = 1.44269504f;
    const float CLIP2 = 14.4269504f;                 // 10 * log2(e)

    unsigned qu = *reinterpret_cast<const unsigned*>(Qb + (size_t)n * D + lane * 2);
    float q0 = bfe0(qu) * L2E, q1 = bfe1(qu) * L2E;

    int start = offsets[n];
    int cnt   = counts[n];
    unsigned lane8 = (unsigned)(lane << 3);

    float acc0 = 0.f, acc1 = 0.f, nrm = 0.f;
    for (int base = 0; base < cnt; base += 64) {
        int m = cnt - base; if (m > 64) m = 64;
        int moff = (base + lane < cnt) ? (csr_cols[start + base + lane] << 9) : 0;
        int j = 0;
        for (; j + 3 < m; j += 4) {
            int o0 = __shfl(moff, j,     64);
            int o1 = __shfl(moff, j + 1, 64);
            int o2 = __shfl(moff, j + 2, 64);
            int o3 = __shfl(moff, j + 3, 64);
            uint2 kv0 = *reinterpret_cast<const uint2*>(KVb + ((unsigned)o0 | lane8));
            uint2 kv1 = *reinterpret_cast<const uint2*>(KVb + ((unsigned)o1 | lane8));
            uint2 kv2 = *reinterpret_cast<const uint2*>(KVb + ((unsigned)o2 | lane8));
            uint2 kv3 = *reinterpret_cast<const uint2*>(KVb + ((unsigned)o3 | lane8));
            float p0 = q0 * bfe0(kv0.x) + q1 * bfe1(kv0.x);
            float p1 = q0 * bfe0(kv1.x) + q1 * bfe1(kv1.x);
            float p2 = q0 * bfe0(kv2.x) + q1 * bfe1(kv2.x);
            float p3 = q0 * bfe0(kv3.x) + q1 * bfe1(kv3.x);
            p0 = red8(p0); p1 = red8(p1); p2 = red8(p2); p3 = red8(p3);
            float s0 = __builtin_amdgcn_exp2f(fminf(fmaxf(p0, -CLIP2), CLIP2));
            float s1 = __builtin_amdgcn_exp2f(fminf(fmaxf(p1, -CLIP2), CLIP2));
            float s2 = __builtin_amdgcn_exp2f(fminf(fmaxf(p2, -CLIP2), CLIP2));
            float s3 = __builtin_amdgcn_exp2f(fminf(fmaxf(p3, -CLIP2), CLIP2));
            nrm  += (s0 + s1) + (s2 + s3);
            acc0 += s0 * bfe0(kv0.y); acc1 += s0 * bfe1(kv0.y);
            acc0 += s1 * bfe0(kv1.y); acc1 += s1 * bfe1(kv1.y);
            acc0 += s2 * bfe0(kv2.y); acc1 += s2 * bfe1(kv2.y);
            acc0 += s3 * bfe0(kv3.y); acc1 += s3 * bfe1(kv3.y);
        }
        for (; j < m; ++j) {
            int o0 = __shfl(moff, j, 64);
            uint2 kv0 = *reinterpret_cast<const uint2*>(KVb + ((unsigned)o0 | lane8));
            float p0 = red8(q0 * bfe0(kv0.x) + q1 * bfe1(kv0.x));
            float s0 = __builtin_amdgcn_exp2f(fminf(fmaxf(p0, -CLIP2), CLIP2));
            nrm  += s0;
            acc0 += s0 * bfe0(kv0.y);
            acc1 += s0 * bfe1(kv0.y);
        }
    }

    float w = 1.f / (nrm + 1e-8f);
    float2 e2 = *reinterpret_cast<const float2*>(emb + (size_t)n * D + lane * 2);
    float x0 = acc0 * w + e2.x;
    float x1 = acc1 * w + e2.y;

    float ssum = x0 + x1;
#pragma unroll
    for (int off = 32; off; off >>= 1) ssum += __shfl_xor(ssum, off, 64);
    float mean = ssum * (1.0f / 128.0f);
    float d0 = x0 - mean, d1 = x1 - mean;
    float var = d0 * d0 + d1 * d1;
#pragma unroll
    for (int off = 32; off; off >>= 1) var += __shfl_xor(var, off, 64);
    float rs = rsqrtf(var * (1.0f / 128.0f) + 1e-6f);

    float2 g2 = *reinterpret_cast<const float2*>(gamma + lane * 2);
    float2 b2 = *reinterpret_cast<const float2*>(beta + lane * 2);
    float2 o2 = make_float2(d0 * rs * g2.x + b2.x, d1 * rs * g2.y + b2.y);
    *reinterpret_cast<float2*>(out + (size_t)n * D + lane * 2) = o2;
}

// ---------------------------------------------------------------------------
extern "C" void kernel_launch(void* const* d_in, const int* in_sizes, int n_in,
                              void* d_out, int out_size, void* d_ws, size_t ws_size,
                              hipStream_t stream)
{
    const float* emb   = (const float*)d_in[0];
    const float* qW    = (const float*)d_in[1];
    const float* kW    = (const float*)d_in[2];
    const float* vW    = (const float*)d_in[3];
    const float* gamma = (const float*)d_in[4];
    const float* beta  = (const float*)d_in[5];
    const int*   eidx  = (const int*)d_in[6];
    const int*   rows  = eidx;
    const int*   cols  = eidx + N_EDGES;
    float* out = (float*)d_out;

    const size_t ND = (size_t)N_NODES * D;
    bf16* Qb  = (bf16*)d_ws;
    char* KVb = (char*)(Qb + ND);                    // N_NODES * 512 B (K/V interleaved)
    int* counts     = (int*)(KVb + (size_t)N_NODES * 512);
    int* offsets    = counts + N_NODES;
    int* cursor     = offsets + N_NODES;
    int* block_sums = cursor + N_NODES;
    int* csr_cols   = block_sums + 512;
    unsigned short* Wf = (unsigned short*)(csr_cols + N_EDGES);  // 3*32768 ushort

    prep_kernel<<<NB, 256, 0, stream>>>(qW, kW, vW, Wf, counts);
    qkv_mfma<<<NBQ, 256, 0, stream>>>(emb, Wf, Qb, KVb, rows, counts);

    scan_block<<<NB, 256, 0, stream>>>(counts, offsets, block_sums);
    scan_tops<<<1, 512, 0, stream>>>(block_sums);
    scan_add<<<NB, 256, 0, stream>>>(offsets, block_sums, cursor);
    scatter_kernel<<<(N_EDGES + 255) / 256, 256, 0, stream>>>(rows, cols, cursor, csr_cols);

    fused_node<<<(N_NODES + 3) / 4, 256, 0, stream>>>(
        Qb, KVb, offsets, counts, csr_cols, emb, gamma, beta, out);
}

// Round 4
// 283.803 us; speedup vs baseline: 1.1966x; 1.0049x over previous
//
#include <hip/hip_runtime.h>
#include <hip/hip_bf16.h>

#define N_NODES 100000
#define N_EDGES 800000
#define D 128
#define NH 8
#define NB ((N_NODES + 255) / 256)   // 391 scan blocks
#define NBQ ((N_NODES + 63) / 64)    // 1563 qkv blocks (64 rows each)

typedef __hip_bfloat16 bf16;
typedef __bf16 bf16x8 __attribute__((ext_vector_type(8)));
typedef float  f32x4  __attribute__((ext_vector_type(4)));

__device__ __forceinline__ unsigned short f2bu(float x) {
    bf16 b = __float2bfloat16(x);
    return *reinterpret_cast<unsigned short*>(&b);
}
__device__ __forceinline__ float bu2f(unsigned short u) {
    return __uint_as_float(((unsigned)u) << 16);
}
__device__ __forceinline__ float bfe0(unsigned u) { return __uint_as_float(u << 16); }
__device__ __forceinline__ float bfe1(unsigned u) { return __uint_as_float(u & 0xffff0000u); }

union frag_u { unsigned short u[8]; bf16x8 v; };

// DPP-based add of a lane-shuffled copy (VALU pipe; no DS traffic).
template<int CTRL>
__device__ __forceinline__ float dpp_add(float x) {
    int y = __builtin_amdgcn_mov_dpp(__float_as_int(x), CTRL, 0xf, 0xf, true);
    return x + __int_as_float(y);
}
// Sum over each aligned 8-lane group: xor1, xor2, xor7 spans the 3-bit group.
__device__ __forceinline__ float red8(float x) {
    x = dpp_add<0xB1>(x);    // quad_perm [1,0,3,2]  -> lane ^ 1
    x = dpp_add<0x4E>(x);    // quad_perm [2,3,0,1]  -> lane ^ 2
    x = dpp_add<0x141>(x);   // row_half_mirror      -> lane ^ 7
    return x;
}

// ---------------------------------------------------------------------------
// Kernel 0: lay W out in MFMA B-fragment order (hi/lo bf16 split) AND zero
// the per-node edge counters.  Matrix 0 = Q.  Matrices 1,2 = KV-low/KV-high
// with columns permuted so the MFMA output row IS the fused dword-interleaved
// KV layout ({k_2d,k_2d+1} at byte d*8, {v_2d,v_2d+1} at +4)  ->  epilogue
// stores stay contiguous/coalesced.
// ---------------------------------------------------------------------------
__global__ __launch_bounds__(256) void prep_kernel(
    const float* __restrict__ Wq, const float* __restrict__ Wk, const float* __restrict__ Wv,
    unsigned short* __restrict__ Wf, int* __restrict__ counts)
{
    int t = blockIdx.x * 256 + threadIdx.x;
    if (t < N_NODES) counts[t] = 0;
    if (t < 3 * 32 * 64) {
        int lane = t & 63;
        int ct   = (t >> 6) & 31;
        int mat  = t >> 11;
        int c  = ct >> 3, tt = ct & 7;
        int n  = tt * 16 + (lane & 15);
        int kb = c * 32 + (lane >> 4) * 8;
        const float* W;
        int col;
        if (mat == 0) {
            W = Wq; col = n;
        } else {
            int g = (mat - 1) * 128 + n;
            W = (g & 2) ? Wv : Wk;
            col = ((g >> 2) << 1) | (g & 1);
        }
        unsigned short* dst = Wf + (size_t)mat * 32768 + (size_t)ct * 1024 + (size_t)lane * 8;
#pragma unroll
        for (int j = 0; j < 8; ++j) {
            float w  = W[(size_t)(kb + j) * D + col];
            unsigned short hb = f2bu(w);
            float lo = w - bu2f(hb);
            dst[j]       = hb;          // hi (part 0)
            dst[512 + j] = f2bu(lo);    // lo (part 1)
        }
    }
}

// ---------------------------------------------------------------------------
// Kernel 1: fused Q/KV projection via bf16 MFMA with hi/lo precision split.
// 64 rows/block, 16 rows/wave; 1563 blocks -> 5 resident blocks/CU (LDS-
// capped), staging stalls hide under other blocks' MFMA.  Edge histogram
// fused into the prologue.   (unchanged this round)
// ---------------------------------------------------------------------------
__global__ __launch_bounds__(256) void qkv_mfma(
    const float* __restrict__ E, const unsigned short* __restrict__ Wf,
    bf16* __restrict__ Q, char* __restrict__ KVb,
    const int* __restrict__ rows, int* __restrict__ counts)
{
    __shared__ unsigned short bsh[16384];   // 32 KB: B staging, then epilogue
    const int tid  = threadIdx.x;
    const int wave = tid >> 6;
    const int lane = tid & 63;
    const int r0w  = blockIdx.x * 64 + wave * 16;   // this wave's 16 rows

    // --- edge histogram slice: 2 edges/thread, 1563*512 >= 800000 ---
    {
        int e0 = (blockIdx.x * 256 + tid) * 2;
        if (e0 < N_EDGES) {
            int2 r2 = *reinterpret_cast<const int2*>(rows + e0);
            atomicAdd(&counts[r2.x], 1);
            atomicAdd(&counts[r2.y], 1);
        }
    }

    const int am = lane & 15;    // A row within 16-tile
    const int aq = lane >> 4;    // k quad

    // Load + split A fragments: 4 k-chunks x 8 bf16 (hi/lo).
    frag_u ahi[4], alo[4];
    {
        int row = r0w + am;
        if (row >= N_NODES) row = N_NODES - 1;     // clamp; stores are guarded
        const float* erow = E + (size_t)row * D + aq * 8;
#pragma unroll
        for (int c = 0; c < 4; ++c) {
            float4 e0 = *reinterpret_cast<const float4*>(erow + c * 32);
            float4 e1 = *reinterpret_cast<const float4*>(erow + c * 32 + 4);
            float ef[8] = {e0.x, e0.y, e0.z, e0.w, e1.x, e1.y, e1.z, e1.w};
#pragma unroll
            for (int j = 0; j < 8; ++j) {
                unsigned short hb = f2bu(ef[j]);
                ahi[c].u[j] = hb;
                alo[c].u[j] = f2bu(ef[j] - bu2f(hb));
            }
        }
    }

#pragma unroll
    for (int mat = 0; mat < 3; ++mat) {
        f32x4 acc[8];
#pragma unroll
        for (int t = 0; t < 8; ++t)
            acc[t] = (f32x4){0.f, 0.f, 0.f, 0.f};

        const unsigned short* wm = Wf + (size_t)mat * 32768;

#pragma unroll
        for (int half = 0; half < 2; ++half) {
            __syncthreads();    // previous users of bsh are done
            // Stage 32 KB (c = 2*half .. 2*half+1): 2048 uint4, 8 per thread.
            const uint4* src = reinterpret_cast<const uint4*>(wm + half * 16384);
            uint4* dstv = reinterpret_cast<uint4*>(bsh);
#pragma unroll
            for (int k = 0; k < 8; ++k)
                dstv[k * 256 + tid] = src[k * 256 + tid];
            __syncthreads();

#pragma unroll
            for (int t = 0; t < 8; ++t) {
#pragma unroll
                for (int cc = 0; cc < 2; ++cc) {
                    const unsigned short* bp = bsh + (cc * 8 + t) * 1024 + lane * 8;
                    bf16x8 bhi = *reinterpret_cast<const bf16x8*>(bp);
                    bf16x8 blo = *reinterpret_cast<const bf16x8*>(bp + 512);
                    const int c = half * 2 + cc;
                    acc[t] = __builtin_amdgcn_mfma_f32_16x16x32_bf16(alo[c].v, bhi, acc[t], 0, 0, 0);
                    acc[t] = __builtin_amdgcn_mfma_f32_16x16x32_bf16(ahi[c].v, blo, acc[t], 0, 0, 0);
                    acc[t] = __builtin_amdgcn_mfma_f32_16x16x32_bf16(ahi[c].v, bhi, acc[t], 0, 0, 0);
                }
            }
        }
        __syncthreads();   // all waves done reading B; bsh reusable per-wave

        // Epilogue: C-frags -> per-wave LDS slice (stride 136) -> coalesced
        // dwordx4 stores.  C layout: col = t*16+am, row = aq*4+r.
        unsigned short* ob = bsh + wave * 2176;   // 16 rows x 136
#pragma unroll
        for (int t = 0; t < 8; ++t)
#pragma unroll
            for (int r = 0; r < 4; ++r)
                ob[(aq * 4 + r) * 136 + t * 16 + am] = f2bu(acc[t][r]);
        {
            const int row = lane >> 2, c4 = lane & 3;
            int grow = r0w + row;
            if (grow < N_NODES) {
                const uint4* srcb = reinterpret_cast<const uint4*>(ob + row * 136 + c4 * 32);
                uint4 d0 = srcb[0], d1 = srcb[1], d2 = srcb[2], d3 = srcb[3];
                uint4* dst;
                if (mat == 0)
                    dst = reinterpret_cast<uint4*>(Q + (size_t)grow * D + c4 * 32);
                else
                    dst = reinterpret_cast<uint4*>(KVb + ((size_t)grow << 9)
                                                   + (size_t)(mat - 1) * 256 + (size_t)c4 * 64);
                dst[0] = d0; dst[1] = d1; dst[2] = d2; dst[3] = d3;
            }
        }
    }
}

// ---------------------------------------------------------------------------
// CSR build: 3-kernel exclusive scan -> scatter  (histogram in qkv_mfma)
// ---------------------------------------------------------------------------
__global__ __launch_bounds__(256) void scan_block(
    const int* __restrict__ counts, int* __restrict__ scanned, int* __restrict__ block_sums)
{
    __shared__ int s[256];
    int tid = threadIdx.x;
    int i = blockIdx.x * 256 + tid;
    int v = (i < N_NODES) ? counts[i] : 0;
    s[tid] = v;
    __syncthreads();
#pragma unroll
    for (int off = 1; off < 256; off <<= 1) {
        int t = (tid >= off) ? s[tid - off] : 0;
        __syncthreads();
        s[tid] += t;
        __syncthreads();
    }
    if (i < N_NODES) scanned[i] = s[tid] - v;
    if (tid == 255) block_sums[blockIdx.x] = s[255];
}

__global__ __launch_bounds__(512) void scan_tops(int* __restrict__ block_sums)
{
    __shared__ int s[512];
    int tid = threadIdx.x;
    int v = (tid < NB) ? block_sums[tid] : 0;
    s[tid] = v;
    __syncthreads();
#pragma unroll
    for (int off = 1; off < 512; off <<= 1) {
        int t = (tid >= off) ? s[tid - off] : 0;
        __syncthreads();
        s[tid] += t;
        __syncthreads();
    }
    if (tid < NB) block_sums[tid] = s[tid] - v;
}

__global__ __launch_bounds__(256) void scan_add(
    int* __restrict__ scanned, const int* __restrict__ block_sums, int* __restrict__ cursor)
{
    int i = blockIdx.x * 256 + threadIdx.x;
    if (i < N_NODES) {
        int o = scanned[i] + block_sums[blockIdx.x];
        scanned[i] = o;
        cursor[i]  = o;
    }
}

__global__ __launch_bounds__(256) void scatter_kernel(
    const int* __restrict__ rows, const int* __restrict__ cols,
    int* __restrict__ cursor, int* __restrict__ csr_cols)
{
    int e = blockIdx.x * 256 + threadIdx.x;
    if (e < N_EDGES) {
        int pos = atomicAdd(&cursor[rows[e]], 1);
        csr_cols[pos] = cols[e];
    }
}

// ---------------------------------------------------------------------------
// Fused per-node attention + residual + LayerNorm. One wave per node.
// Gather-latency-bound -> this round deepens MLP:
//  - 8-deep edge unroll (8 concurrent dwordx2 gathers), then 4, then singles.
//  - v_readlane (uniform offset -> SGPR) instead of __shfl: saddr-form loads,
//    no per-edge ds_bpermute / address VALU.
//  - split accumulator banks to break serial FMA chains.
//  - single-pass LayerNorm (sum + sumsq, interleaved shuffle chains).
// ---------------------------------------------------------------------------
__device__ __forceinline__ void edge_body(
    const char* __restrict__ KVb, int off, unsigned lane8,
    float q0, float q1, float CLIP2,
    float& acc0, float& acc1, float& nrm)
{
    uint2 kv = *reinterpret_cast<const uint2*>(KVb + (unsigned)off + lane8);
    float p = q0 * bfe0(kv.x) + q1 * bfe1(kv.x);
    p = red8(p);
    float s = __builtin_amdgcn_exp2f(fminf(fmaxf(p, -CLIP2), CLIP2));
    nrm  += s;
    acc0 += s * bfe0(kv.y);
    acc1 += s * bfe1(kv.y);
}

__global__ __launch_bounds__(256) void fused_node(
    const bf16* __restrict__ Qb, const char* __restrict__ KVb,
    const int* __restrict__ offsets, const int* __restrict__ counts,
    const int* __restrict__ csr_cols,
    const float* __restrict__ emb,
    const float* __restrict__ gamma, const float* __restrict__ beta,
    float* __restrict__ out)
{
    int n = blockIdx.x * 4 + (threadIdx.x >> 6);     // grid covers exactly N_NODES
    int lane = threadIdx.x & 63;

    const float L2E   = 1.44269504f;
    const float CLIP2 = 14.4269504f;                 // 10 * log2(e)

    unsigned qu = *reinterpret_cast<const unsigned*>(Qb + (size_t)n * D + lane * 2);
    float q0 = bfe0(qu) * L2E, q1 = bfe1(qu) * L2E;

    int start = offsets[n];
    int cnt   = counts[n];
    unsigned lane8 = (unsigned)(lane << 3);

    float acc0a = 0.f, acc1a = 0.f, nrma = 0.f;
    float acc0b = 0.f, acc1b = 0.f, nrmb = 0.f;

    for (int base = 0; base < cnt; base += 64) {
        int m = cnt - base; if (m > 64) m = 64;
        int moff = (base + lane < cnt) ? (csr_cols[start + base + lane] << 9) : 0;
        int j = 0;
        for (; j + 7 < m; j += 8) {
            int o0 = __builtin_amdgcn_readlane(moff, j + 0);
            int o1 = __builtin_amdgcn_readlane(moff, j + 1);
            int o2 = __builtin_amdgcn_readlane(moff, j + 2);
            int o3 = __builtin_amdgcn_readlane(moff, j + 3);
            int o4 = __builtin_amdgcn_readlane(moff, j + 4);
            int o5 = __builtin_amdgcn_readlane(moff, j + 5);
            int o6 = __builtin_amdgcn_readlane(moff, j + 6);
            int o7 = __builtin_amdgcn_readlane(moff, j + 7);
            edge_body(KVb, o0, lane8, q0, q1, CLIP2, acc0a, acc1a, nrma);
            edge_body(KVb, o1, lane8, q0, q1, CLIP2, acc0b, acc1b, nrmb);
            edge_body(KVb, o2, lane8, q0, q1, CLIP2, acc0a, acc1a, nrma);
            edge_body(KVb, o3, lane8, q0, q1, CLIP2, acc0b, acc1b, nrmb);
            edge_body(KVb, o4, lane8, q0, q1, CLIP2, acc0a, acc1a, nrma);
            edge_body(KVb, o5, lane8, q0, q1, CLIP2, acc0b, acc1b, nrmb);
            edge_body(KVb, o6, lane8, q0, q1, CLIP2, acc0a, acc1a, nrma);
            edge_body(KVb, o7, lane8, q0, q1, CLIP2, acc0b, acc1b, nrmb);
        }
        for (; j + 3 < m; j += 4) {
            int o0 = __builtin_amdgcn_readlane(moff, j + 0);
            int o1 = __builtin_amdgcn_readlane(moff, j + 1);
            int o2 = __builtin_amdgcn_readlane(moff, j + 2);
            int o3 = __builtin_amdgcn_readlane(moff, j + 3);
            edge_body(KVb, o0, lane8, q0, q1, CLIP2, acc0a, acc1a, nrma);
            edge_body(KVb, o1, lane8, q0, q1, CLIP2, acc0b, acc1b, nrmb);
            edge_body(KVb, o2, lane8, q0, q1, CLIP2, acc0a, acc1a, nrma);
            edge_body(KVb, o3, lane8, q0, q1, CLIP2, acc0b, acc1b, nrmb);
        }
        for (; j < m; ++j) {
            int o0 = __builtin_amdgcn_readlane(moff, j);
            edge_body(KVb, o0, lane8, q0, q1, CLIP2, acc0a, acc1a, nrma);
        }
    }

    float nrm  = nrma + nrmb;
    float acc0 = acc0a + acc0b;
    float acc1 = acc1a + acc1b;

    float w = 1.f / (nrm + 1e-8f);
    float2 e2 = *reinterpret_cast<const float2*>(emb + (size_t)n * D + lane * 2);
    float x0 = acc0 * w + e2.x;
    float x1 = acc1 * w + e2.y;

    // single-pass LayerNorm: reduce sum and sumsq together (independent chains)
    float s1 = x0 + x1;
    float s2 = x0 * x0 + x1 * x1;
#pragma unroll
    for (int off = 32; off; off >>= 1) {
        s1 += __shfl_xor(s1, off, 64);
        s2 += __shfl_xor(s2, off, 64);
    }
    float mean = s1 * (1.0f / 128.0f);
    float var  = fmaxf(s2 * (1.0f / 128.0f) - mean * mean, 0.f);
    float rs = rsqrtf(var + 1e-6f);

    float d0 = x0 - mean, d1 = x1 - mean;
    float2 g2 = *reinterpret_cast<const float2*>(gamma + lane * 2);
    float2 b2 = *reinterpret_cast<const float2*>(beta + lane * 2);
    float2 o2 = make_float2(d0 * rs * g2.x + b2.x, d1 * rs * g2.y + b2.y);
    *reinterpret_cast<float2*>(out + (size_t)n * D + lane * 2) = o2;
}

// ---------------------------------------------------------------------------
extern "C" void kernel_launch(void* const* d_in, const int* in_sizes, int n_in,
                              void* d_out, int out_size, void* d_ws, size_t ws_size,
                              hipStream_t stream)
{
    const float* emb   = (const float*)d_in[0];
    const float* qW    = (const float*)d_in[1];
    const float* kW    = (const float*)d_in[2];
    const float* vW    = (const float*)d_in[3];
    const float* gamma = (const float*)d_in[4];
    const float* beta  = (const float*)d_in[5];
    const int*   eidx  = (const int*)d_in[6];
    const int*   rows  = eidx;
    const int*   cols  = eidx + N_EDGES;
    float* out = (float*)d_out;

    const size_t ND = (size_t)N_NODES * D;
    bf16* Qb  = (bf16*)d_ws;
    char* KVb = (char*)(Qb + ND);                    // N_NODES * 512 B (K/V interleaved)
    int* counts     = (int*)(KVb + (size_t)N_NODES * 512);
    int* offsets    = counts + N_NODES;
    int* cursor     = offsets + N_NODES;
    int* block_sums = cursor + N_NODES;
    int* csr_cols   = block_sums + 512;
    unsigned short* Wf = (unsigned short*)(csr_cols + N_EDGES);  // 3*32768 ushort

    prep_kernel<<<NB, 256, 0, stream>>>(qW, kW, vW, Wf, counts);
    qkv_mfma<<<NBQ, 256, 0, stream>>>(emb, Wf, Qb, KVb, rows, counts);

    scan_block<<<NB, 256, 0, stream>>>(counts, offsets, block_sums);
    scan_tops<<<1, 512, 0, stream>>>(block_sums);
    scan_add<<<NB, 256, 0, stream>>>(offsets, block_sums, cursor);
    scatter_kernel<<<(N_EDGES + 255) / 256, 256, 0, stream>>>(rows, cols, cursor, csr_cols);

    fused_node<<<(N_NODES + 3) / 4, 256, 0, stream>>>(
        Qb, KVb, offsets, counts, csr_cols, emb, gamma, beta, out);
}